// Round 15
// baseline (180.638 us; speedup 1.0000x reference)
//
#include <hip/hip_runtime.h>

typedef unsigned short u16;
typedef unsigned int u32;
typedef __attribute__((ext_vector_type(8))) __bf16 bf16x8;
typedef __attribute__((ext_vector_type(4))) __bf16 bf16x4;
typedef __attribute__((ext_vector_type(4))) float f32x4;

#define GLD_AS1 const __attribute__((address_space(1))) void*
#define GLD_AS3 __attribute__((address_space(3))) void*

__device__ __forceinline__ u16 f2b(float f) {
  u32 u = __builtin_bit_cast(u32, f);
  u += 0x7fffu + ((u >> 16) & 1u);   // RNE
  return (u16)(u >> 16);
}

// ---------- 1+2. fused prep: x f32->bf16 cvt + both weight transposes ----------
// blocks [0,8192): cvt x; [8192,11264): w_qkv transpose; [11264,12288): w_out.
__global__ void prep_kernel(const float* __restrict__ x, u16* __restrict__ xb,
                            const float* __restrict__ w_qkv, u16* __restrict__ wqkvt,
                            const float* __restrict__ w_out, u16* __restrict__ woutt) {
  __shared__ float tile[32][33];
  const int bid = blockIdx.x;
  const int tid = threadIdx.x;
  if (bid < 8192) {
    int i4 = (bid * 256 + tid) * 4;
    float4 v = *(const float4*)(x + i4);
    ushort4 o;
    o.x = f2b(v.x); o.y = f2b(v.y); o.z = f2b(v.z); o.w = f2b(v.w);
    *(ushort4*)(xb + i4) = o;
    return;
  }
  const float* src; u16* dst; int C, R, bx, by;
  if (bid < 11264) {
    int b = bid - 8192;
    src = w_qkv; dst = wqkvt; C = 3072; R = 1024;
    bx = b % 96; by = b / 96;
  } else {
    int b = bid - 11264;
    src = w_out; dst = woutt; C = 1024; R = 1024;
    bx = b % 32; by = b / 32;
  }
  const int c0 = bx * 32, r0 = by * 32;
  const int tx = tid & 31, ty = tid >> 5;
  #pragma unroll
  for (int i = ty; i < 32; i += 8)
    tile[i][tx] = src[(size_t)(r0 + i) * C + c0 + tx];
  __syncthreads();
  #pragma unroll
  for (int i = ty; i < 32; i += 8)
    dst[(size_t)(c0 + i) * R + r0 + tx] = f2b(tile[tx][i]);
}

// ---------- 3/6. GEMM: A[M,K] bf16 @ Bt[N,K]^T + bias ----------
// 128x128 tile, BK=64, 4 waves, single-buffer 2-barrier loop, 32 KB LDS.
// MODE 0: qkv routing epilogue -- q pre-scaled by softmax scale, v written
// DIRECTLY in k-permuted V^T layout. MODE 1: f32 row-major out.
template <int MODE>
__global__ __launch_bounds__(256)
void gemm_kernel(const u16* __restrict__ A, const u16* __restrict__ Bt,
                 const float* __restrict__ bias,
                 u16* __restrict__ qo, u16* __restrict__ ko, u16* __restrict__ vo,
                 float* __restrict__ outF, int N, int K) {
  __shared__ char As[16384];
  __shared__ char Bs[16384];
  const int tid = threadIdx.x;
  const int lane = tid & 63, wave = tid >> 6;

  const int m0 = blockIdx.x * 128, n0 = blockIdx.y * 128;
  const int wm = (wave >> 1) * 64, wn = (wave & 1) * 64;
  const int lr = lane & 15, lg = lane >> 4;

  const int rB = tid >> 3;                               // 0..31
  const int cB = ((tid & 7) * 16) ^ ((rB & 7) << 4);     // pre-swizzled src byte

  const size_t strideK = (size_t)K * 2;
  const char* Ab = (const char*)(A + (size_t)m0 * K);
  const char* Bb = (const char*)(Bt + (size_t)n0 * K);

  f32x4 acc[4][4] = {};
  const int swr = (lr & 7) << 4;

  const int nk = K >> 6;
  for (int kt = 0; kt < nk; ++kt) {
    #pragma unroll
    for (int i = 0; i < 4; ++i)
      __builtin_amdgcn_global_load_lds(
          (GLD_AS1)(Ab + (size_t)(i * 32 + rB) * strideK + kt * 128 + cB),
          (GLD_AS3)(As + i * 4096 + tid * 16), 16, 0, 0);
    #pragma unroll
    for (int i = 0; i < 4; ++i)
      __builtin_amdgcn_global_load_lds(
          (GLD_AS1)(Bb + (size_t)(i * 32 + rB) * strideK + kt * 128 + cB),
          (GLD_AS3)(Bs + i * 4096 + tid * 16), 16, 0, 0);
    __syncthreads();

    bf16x8 af[4][2], bfr[4][2];
    #pragma unroll
    for (int m = 0; m < 4; ++m) {
      const int row = wm + m * 16 + lr;
      #pragma unroll
      for (int s = 0; s < 2; ++s)
        af[m][s] = *(const bf16x8*)(As + row * 128 + ((s * 64 + lg * 16) ^ swr));
    }
    #pragma unroll
    for (int n = 0; n < 4; ++n) {
      const int row = wn + n * 16 + lr;
      #pragma unroll
      for (int s = 0; s < 2; ++s)
        bfr[n][s] = *(const bf16x8*)(Bs + row * 128 + ((s * 64 + lg * 16) ^ swr));
    }
    __builtin_amdgcn_s_setprio(1);
    #pragma unroll
    for (int m = 0; m < 4; ++m)
      #pragma unroll
      for (int n = 0; n < 4; ++n) {
        acc[m][n] = __builtin_amdgcn_mfma_f32_16x16x32_bf16(af[m][0], bfr[n][0], acc[m][n], 0, 0, 0);
        acc[m][n] = __builtin_amdgcn_mfma_f32_16x16x32_bf16(af[m][1], bfr[n][1], acc[m][n], 0, 0, 0);
      }
    __builtin_amdgcn_s_setprio(0);
    __syncthreads();
  }

  if (MODE == 0) {
    const int b = m0 >> 11;     // tile never crosses a batch boundary (2048 | 128)
    #pragma unroll
    for (int n = 0; n < 4; ++n) {
      const int col = n0 + wn + n * 16 + lr;
      const float bv = bias[col];
      const int which = col >> 10, c = col & 1023;
      const int h = c >> 6, d = c & 63;
      #pragma unroll
      for (int m = 0; m < 4; ++m) {
        const int rowb = m0 + wm + m * 16 + lg * 4;
        const int t0 = rowb & 2047;
        if (which == 2) {
          // v: direct k-permuted V^T store [bh][d][tperm], 4 consecutive t -> 8B
          const int tp = (t0 & ~31) | (8 * ((t0 >> 2) & 3) + 4 * ((t0 >> 4) & 1));
          ushort4 q4;
          q4.x = f2b(acc[m][n][0] + bv);
          q4.y = f2b(acc[m][n][1] + bv);
          q4.z = f2b(acc[m][n][2] + bv);
          q4.w = f2b(acc[m][n][3] + bv);
          *(ushort4*)&vo[((size_t)(b * 16 + h) * 64 + d) * 2048 + tp] = q4;
        } else {
          u16* dst = (which == 0) ? qo : ko;
          const float scl = (which == 0) ? 0.18033688011112042f : 1.0f;
          #pragma unroll
          for (int j = 0; j < 4; ++j) {
            float val = (acc[m][n][j] + bv) * scl;
            dst[((size_t)(b * 16 + h) * 2048 + (t0 + j)) * 64 + d] = f2b(val);
          }
        }
      }
    }
  } else {
    #pragma unroll
    for (int n = 0; n < 4; ++n) {
      const int col = n0 + wn + n * 16 + lr;
      const float bv = bias[col];
      #pragma unroll
      for (int m = 0; m < 4; ++m) {
        const int rowb = m0 + wm + m * 16 + lg * 4;
        #pragma unroll
        for (int j = 0; j < 4; ++j)
          outF[(size_t)(rowb + j) * N + col] = acc[m][n][j] + bv;
      }
    }
  }
}

// ---------- 5. flash attention ----------
// grid (64 bh, 8 qtiles of 256), 8 waves/block (512 thr); wave owns 32 q.
// 3-buffer K/V LDS pipeline, depth-2 prefetch, counted vmcnt. XCD-local K/V.
// Swapped QK^T keeps P lane-local; V k-columns pre-permuted (qkv epilogue)
// so each PV A-frag is ONE ds_read_b128.
// l accumulated on the VALU (f32x4 partials + 2 final shuffles) -- frees 20%
// of the MFMA pipe (the old ones-MFMA cost 4 of 20 MFMAs/wave-kt).
__global__ __launch_bounds__(512)
void attn_kernel(const u16* __restrict__ Q, const u16* __restrict__ Kg,
                 const u16* __restrict__ Vt, u16* __restrict__ att) {
  const int tid = threadIdx.x;
  const int wave = tid >> 6, lane = tid & 63;
  const int lr = lane & 15, lg = lane >> 4;
  const int bh = blockIdx.x;
  const int q0 = blockIdx.y * 256;
  const int b = bh >> 4, h = bh & 15;

  const u16* Qh = Q + (size_t)bh * 2048 * 64;
  const char* Khb = (const char*)(Kg + (size_t)bh * 2048 * 64);
  const char* Vhb = (const char*)(Vt + (size_t)bh * 64 * 2048);

  __shared__ u16 Ks[3][64 * 64];   // [k=64][d=64] rows 128B, 3-bit XOR swizzle
  __shared__ u16 Vs[3][64 * 64];   // [d=64][kperm=64] rows 128B, 3-bit XOR swizzle

  const int rS = tid >> 3;                               // 0..63 row
  const int cS = ((tid & 7) * 16) ^ ((rS & 7) << 4);     // pre-swizzled src byte

  bf16x8 qf[2][2];
  #pragma unroll
  for (int m = 0; m < 2; ++m)
    #pragma unroll
    for (int s = 0; s < 2; ++s)
      qf[m][s] = *(const bf16x8*)(Qh + (size_t)(q0 + wave * 32 + m * 16 + lr) * 64 + s * 32 + lg * 8);

  f32x4 acc[2][4] = {};
  f32x4 rlv[2] = {};   // per-lane l partials: q=lr, k-subsets per lg

#define STAGE(T, BUF)                                                          \
  {                                                                            \
    __builtin_amdgcn_global_load_lds(                                          \
        (GLD_AS1)(Khb + (size_t)((T) * 64 + rS) * 128 + cS),                   \
        (GLD_AS3)((char*)Ks[BUF] + tid * 16), 16, 0, 0);                       \
    __builtin_amdgcn_global_load_lds(                                          \
        (GLD_AS1)(Vhb + (size_t)rS * 4096 + (T) * 128 + cS),                   \
        (GLD_AS3)((char*)Vs[BUF] + tid * 16), 16, 0, 0);                       \
  }

  STAGE(0, 0);
  STAGE(1, 1);

  for (int kt = 0; kt < 32; ++kt) {
    if (kt == 31) { asm volatile("s_waitcnt vmcnt(0)" ::: "memory"); }
    else          { asm volatile("s_waitcnt vmcnt(2)" ::: "memory"); }
    __builtin_amdgcn_sched_barrier(0);
    __builtin_amdgcn_s_barrier();
    if (kt < 30) STAGE(kt + 2, (kt + 2) % 3);
    const int cur = kt % 3;

    #pragma unroll
    for (int ks = 0; ks < 2; ++ks) {
      f32x4 sf0[2] = {}, sf1[2] = {};
      __builtin_amdgcn_s_setprio(1);
      #pragma unroll
      for (int s = 0; s < 2; ++s) {
        bf16x8 kf0 = *(const bf16x8*)((const char*)Ks[cur] + (2 * ks * 16 + lr) * 128 +
                                      ((s * 64 + lg * 16) ^ ((lr & 7) << 4)));
        sf0[0] = __builtin_amdgcn_mfma_f32_16x16x32_bf16(kf0, qf[0][s], sf0[0], 0, 0, 0);
        sf0[1] = __builtin_amdgcn_mfma_f32_16x16x32_bf16(kf0, qf[1][s], sf0[1], 0, 0, 0);
        bf16x8 kf1 = *(const bf16x8*)((const char*)Ks[cur] + ((2 * ks + 1) * 16 + lr) * 128 +
                                      ((s * 64 + lg * 16) ^ ((lr & 7) << 4)));
        sf1[0] = __builtin_amdgcn_mfma_f32_16x16x32_bf16(kf1, qf[0][s], sf1[0], 0, 0, 0);
        sf1[1] = __builtin_amdgcn_mfma_f32_16x16x32_bf16(kf1, qf[1][s], sf1[1], 0, 0, 0);
      }
      __builtin_amdgcn_s_setprio(0);

      // softmax numerator in-register; l partials on the VALU
      bf16x8 pa[2];
      #pragma unroll
      for (int m = 0; m < 2; ++m) {
        f32x4 p0, p1;
        #pragma unroll
        for (int j = 0; j < 4; ++j) p0[j] = __builtin_amdgcn_exp2f(sf0[m][j]);
        #pragma unroll
        for (int j = 0; j < 4; ++j) p1[j] = __builtin_amdgcn_exp2f(sf1[m][j]);
        rlv[m] += p0;
        rlv[m] += p1;
        #pragma unroll
        for (int j = 0; j < 4; ++j) { pa[m][j] = (__bf16)p0[j]; pa[m][4 + j] = (__bf16)p1[j]; }
      }

      __builtin_amdgcn_s_setprio(1);
      #pragma unroll
      for (int d = 0; d < 4; ++d) {
        const int rv = d * 16 + lr;
        bf16x8 vf = *(const bf16x8*)((const char*)Vs[cur] + rv * 128 +
                                     ((64 * ks + 16 * lg) ^ ((lr & 7) << 4)));
        acc[0][d] = __builtin_amdgcn_mfma_f32_16x16x32_bf16(vf, pa[0], acc[0][d], 0, 0, 0);
        acc[1][d] = __builtin_amdgcn_mfma_f32_16x16x32_bf16(vf, pa[1], acc[1][d], 0, 0, 0);
      }
      __builtin_amdgcn_s_setprio(0);
    }
  }

  // l: horizontal over j, then across the 4 lg copies of each q-row
  #pragma unroll
  for (int m = 0; m < 2; ++m) {
    float rl = rlv[m][0] + rlv[m][1] + rlv[m][2] + rlv[m][3];
    rl += __shfl_xor(rl, 16);
    rl += __shfl_xor(rl, 32);
    const float inv = 1.0f / rl;
    const int t = q0 + wave * 32 + m * 16 + lr;
    #pragma unroll
    for (int d = 0; d < 4; ++d) {
      bf16x4 ov;
      #pragma unroll
      for (int j = 0; j < 4; ++j) ov[j] = (__bf16)(acc[m][d][j] * inv);
      *(bf16x4*)&att[((size_t)b * 2048 + t) * 1024 + h * 64 + d * 16 + lg * 4] = ov;
    }
  }
#undef STAGE
}

extern "C" void kernel_launch(void* const* d_in, const int* in_sizes, int n_in,
                              void* d_out, int out_size, void* d_ws, size_t ws_size,
                              hipStream_t stream) {
  const float* x     = (const float*)d_in[0];
  const float* w_qkv = (const float*)d_in[1];
  const float* b_qkv = (const float*)d_in[2];
  const float* w_out = (const float*)d_in[3];
  const float* b_out = (const float*)d_in[4];
  float* out = (float*)d_out;

  char* ws = (char*)d_ws;
  const size_t MB = 1024 * 1024;
  u16* xb    = (u16*)(ws);             // 16 MB x bf16 -- dead after qkv gemm
  u16* attb  = xb;                     // alias: attn output reuses xb
  u16* wqkvt = (u16*)(ws + 16 * MB);   // 6 MB  [3072][1024]
  u16* woutt = (u16*)(ws + 22 * MB);   // 2 MB  [1024][1024]
  u16* qb    = (u16*)(ws + 24 * MB);   // 16 MB [bh][2048][64]
  u16* kb    = (u16*)(ws + 40 * MB);   // 16 MB
  u16* vtb   = (u16*)(ws + 56 * MB);   // 16 MB [bh][64][2048] (k-permuted V^T)

  // fused prep: cvt x (8192 blocks) + w_qkv transpose (3072) + w_out (1024)
  prep_kernel<<<12288, 256, 0, stream>>>(x, xb, w_qkv, wqkvt, w_out, woutt);

  // qkv GEMM (bf16 A); v written directly as k-permuted V^T
  gemm_kernel<0><<<dim3(8192 / 128, 3072 / 128), 256, 0, stream>>>(
      xb, wqkvt, b_qkv, qb, kb, vtb, nullptr, 3072, 1024);

  attn_kernel<<<dim3(64, 8), 512, 0, stream>>>(qb, kb, vtb, attb);

  gemm_kernel<1><<<dim3(8192 / 128, 1024 / 128), 256, 0, stream>>>(
      attb, woutt, b_out, nullptr, nullptr, nullptr, out, 1024, 1024);
}

// Round 16
// 171.471 us; speedup vs baseline: 1.0535x; 1.0535x over previous
//
#include <hip/hip_runtime.h>

typedef unsigned short u16;
typedef unsigned int u32;
typedef __attribute__((ext_vector_type(8))) __bf16 bf16x8;
typedef __attribute__((ext_vector_type(4))) __bf16 bf16x4;
typedef __attribute__((ext_vector_type(4))) float f32x4;

#define GLD_AS1 const __attribute__((address_space(1))) void*
#define GLD_AS3 __attribute__((address_space(3))) void*

__device__ __forceinline__ u16 f2b(float f) {
  u32 u = __builtin_bit_cast(u32, f);
  u += 0x7fffu + ((u >> 16) & 1u);   // RNE
  return (u16)(u >> 16);
}

// ---------- 1+2. fused prep: x f32->bf16 cvt + both weight transposes ----------
// blocks [0,8192): cvt x; [8192,11264): w_qkv transpose; [11264,12288): w_out.
__global__ void prep_kernel(const float* __restrict__ x, u16* __restrict__ xb,
                            const float* __restrict__ w_qkv, u16* __restrict__ wqkvt,
                            const float* __restrict__ w_out, u16* __restrict__ woutt) {
  __shared__ float tile[32][33];
  const int bid = blockIdx.x;
  const int tid = threadIdx.x;
  if (bid < 8192) {
    int i4 = (bid * 256 + tid) * 4;
    float4 v = *(const float4*)(x + i4);
    ushort4 o;
    o.x = f2b(v.x); o.y = f2b(v.y); o.z = f2b(v.z); o.w = f2b(v.w);
    *(ushort4*)(xb + i4) = o;
    return;
  }
  const float* src; u16* dst; int C, R, bx, by;
  if (bid < 11264) {
    int b = bid - 8192;
    src = w_qkv; dst = wqkvt; C = 3072; R = 1024;
    bx = b % 96; by = b / 96;
  } else {
    int b = bid - 11264;
    src = w_out; dst = woutt; C = 1024; R = 1024;
    bx = b % 32; by = b / 32;
  }
  const int c0 = bx * 32, r0 = by * 32;
  const int tx = tid & 31, ty = tid >> 5;
  #pragma unroll
  for (int i = ty; i < 32; i += 8)
    tile[i][tx] = src[(size_t)(r0 + i) * C + c0 + tx];
  __syncthreads();
  #pragma unroll
  for (int i = ty; i < 32; i += 8)
    dst[(size_t)(c0 + i) * R + r0 + tx] = f2b(tile[tx][i]);
}

// ---------- 3/6. GEMM: A[M,K] bf16 @ Bt[N,K]^T + bias ----------
// 128x128 tile, BK=64, 4 waves, single-buffer 2-barrier loop, 32 KB LDS.
// MODE 0: qkv routing epilogue -- q pre-scaled by softmax scale, v written
// DIRECTLY in k-permuted V^T layout. MODE 1: f32 row-major out.
template <int MODE>
__global__ __launch_bounds__(256)
void gemm_kernel(const u16* __restrict__ A, const u16* __restrict__ Bt,
                 const float* __restrict__ bias,
                 u16* __restrict__ qo, u16* __restrict__ ko, u16* __restrict__ vo,
                 float* __restrict__ outF, int N, int K) {
  __shared__ char As[16384];
  __shared__ char Bs[16384];
  const int tid = threadIdx.x;
  const int lane = tid & 63, wave = tid >> 6;

  const int m0 = blockIdx.x * 128, n0 = blockIdx.y * 128;
  const int wm = (wave >> 1) * 64, wn = (wave & 1) * 64;
  const int lr = lane & 15, lg = lane >> 4;

  const int rB = tid >> 3;                               // 0..31
  const int cB = ((tid & 7) * 16) ^ ((rB & 7) << 4);     // pre-swizzled src byte

  const size_t strideK = (size_t)K * 2;
  const char* Ab = (const char*)(A + (size_t)m0 * K);
  const char* Bb = (const char*)(Bt + (size_t)n0 * K);

  f32x4 acc[4][4] = {};
  const int swr = (lr & 7) << 4;

  const int nk = K >> 6;
  for (int kt = 0; kt < nk; ++kt) {
    #pragma unroll
    for (int i = 0; i < 4; ++i)
      __builtin_amdgcn_global_load_lds(
          (GLD_AS1)(Ab + (size_t)(i * 32 + rB) * strideK + kt * 128 + cB),
          (GLD_AS3)(As + i * 4096 + tid * 16), 16, 0, 0);
    #pragma unroll
    for (int i = 0; i < 4; ++i)
      __builtin_amdgcn_global_load_lds(
          (GLD_AS1)(Bb + (size_t)(i * 32 + rB) * strideK + kt * 128 + cB),
          (GLD_AS3)(Bs + i * 4096 + tid * 16), 16, 0, 0);
    __syncthreads();

    bf16x8 af[4][2], bfr[4][2];
    #pragma unroll
    for (int m = 0; m < 4; ++m) {
      const int row = wm + m * 16 + lr;
      #pragma unroll
      for (int s = 0; s < 2; ++s)
        af[m][s] = *(const bf16x8*)(As + row * 128 + ((s * 64 + lg * 16) ^ swr));
    }
    #pragma unroll
    for (int n = 0; n < 4; ++n) {
      const int row = wn + n * 16 + lr;
      #pragma unroll
      for (int s = 0; s < 2; ++s)
        bfr[n][s] = *(const bf16x8*)(Bs + row * 128 + ((s * 64 + lg * 16) ^ swr));
    }
    __builtin_amdgcn_s_setprio(1);
    #pragma unroll
    for (int m = 0; m < 4; ++m)
      #pragma unroll
      for (int n = 0; n < 4; ++n) {
        acc[m][n] = __builtin_amdgcn_mfma_f32_16x16x32_bf16(af[m][0], bfr[n][0], acc[m][n], 0, 0, 0);
        acc[m][n] = __builtin_amdgcn_mfma_f32_16x16x32_bf16(af[m][1], bfr[n][1], acc[m][n], 0, 0, 0);
      }
    __builtin_amdgcn_s_setprio(0);
    __syncthreads();
  }

  if (MODE == 0) {
    const int b = m0 >> 11;     // tile never crosses a batch boundary (2048 | 128)
    #pragma unroll
    for (int n = 0; n < 4; ++n) {
      const int col = n0 + wn + n * 16 + lr;
      const float bv = bias[col];
      const int which = col >> 10, c = col & 1023;
      const int h = c >> 6, d = c & 63;
      #pragma unroll
      for (int m = 0; m < 4; ++m) {
        const int rowb = m0 + wm + m * 16 + lg * 4;
        const int t0 = rowb & 2047;
        if (which == 2) {
          // v: direct k-permuted V^T store [bh][d][tperm], 4 consecutive t -> 8B
          const int tp = (t0 & ~31) | (8 * ((t0 >> 2) & 3) + 4 * ((t0 >> 4) & 1));
          ushort4 q4;
          q4.x = f2b(acc[m][n][0] + bv);
          q4.y = f2b(acc[m][n][1] + bv);
          q4.z = f2b(acc[m][n][2] + bv);
          q4.w = f2b(acc[m][n][3] + bv);
          *(ushort4*)&vo[((size_t)(b * 16 + h) * 64 + d) * 2048 + tp] = q4;
        } else {
          u16* dst = (which == 0) ? qo : ko;
          const float scl = (which == 0) ? 0.18033688011112042f : 1.0f;
          #pragma unroll
          for (int j = 0; j < 4; ++j) {
            float val = (acc[m][n][j] + bv) * scl;
            dst[((size_t)(b * 16 + h) * 2048 + (t0 + j)) * 64 + d] = f2b(val);
          }
        }
      }
    }
  } else {
    #pragma unroll
    for (int n = 0; n < 4; ++n) {
      const int col = n0 + wn + n * 16 + lr;
      const float bv = bias[col];
      #pragma unroll
      for (int m = 0; m < 4; ++m) {
        const int rowb = m0 + wm + m * 16 + lg * 4;
        #pragma unroll
        for (int j = 0; j < 4; ++j)
          outF[(size_t)(rowb + j) * N + col] = acc[m][n][j] + bv;
      }
    }
  }
}

// ---------- 5. flash attention ----------
// grid (64 bh, 8 qtiles of 256), 8 waves/block (512 thr); wave owns 32 q.
// 3-buffer K/V LDS pipeline, depth-2 prefetch, counted vmcnt. XCD-local K/V.
// Swapped QK^T keeps P lane-local; V k-columns pre-permuted (qkv epilogue)
// so each PV A-frag is ONE ds_read_b128; l via ones-MFMA (fire-and-forget on
// the matrix pipe -- R15 showed VALU l-accum lengthens the dependency chain).
__global__ __launch_bounds__(512)
void attn_kernel(const u16* __restrict__ Q, const u16* __restrict__ Kg,
                 const u16* __restrict__ Vt, u16* __restrict__ att) {
  const int tid = threadIdx.x;
  const int wave = tid >> 6, lane = tid & 63;
  const int lr = lane & 15, lg = lane >> 4;
  const int bh = blockIdx.x;
  const int q0 = blockIdx.y * 256;
  const int b = bh >> 4, h = bh & 15;

  const u16* Qh = Q + (size_t)bh * 2048 * 64;
  const char* Khb = (const char*)(Kg + (size_t)bh * 2048 * 64);
  const char* Vhb = (const char*)(Vt + (size_t)bh * 64 * 2048);

  __shared__ u16 Ks[3][64 * 64];   // [k=64][d=64] rows 128B, 3-bit XOR swizzle
  __shared__ u16 Vs[3][64 * 64];   // [d=64][kperm=64] rows 128B, 3-bit XOR swizzle

  const int rS = tid >> 3;                               // 0..63 row
  const int cS = ((tid & 7) * 16) ^ ((rS & 7) << 4);     // pre-swizzled src byte

  bf16x8 qf[2][2];
  #pragma unroll
  for (int m = 0; m < 2; ++m)
    #pragma unroll
    for (int s = 0; s < 2; ++s)
      qf[m][s] = *(const bf16x8*)(Qh + (size_t)(q0 + wave * 32 + m * 16 + lr) * 64 + s * 32 + lg * 8);

  bf16x8 ones;
  #pragma unroll
  for (int e = 0; e < 8; ++e) ones[e] = (__bf16)1.0f;

  f32x4 acc[2][4] = {};
  f32x4 accl[2] = {};   // C rows all equal Sum_k P[k][q=lr] -> l lane-uniform

#define STAGE(T, BUF)                                                          \
  {                                                                            \
    __builtin_amdgcn_global_load_lds(                                          \
        (GLD_AS1)(Khb + (size_t)((T) * 64 + rS) * 128 + cS),                   \
        (GLD_AS3)((char*)Ks[BUF] + tid * 16), 16, 0, 0);                       \
    __builtin_amdgcn_global_load_lds(                                          \
        (GLD_AS1)(Vhb + (size_t)rS * 4096 + (T) * 128 + cS),                   \
        (GLD_AS3)((char*)Vs[BUF] + tid * 16), 16, 0, 0);                       \
  }

  STAGE(0, 0);
  STAGE(1, 1);

  for (int kt = 0; kt < 32; ++kt) {
    if (kt == 31) { asm volatile("s_waitcnt vmcnt(0)" ::: "memory"); }
    else          { asm volatile("s_waitcnt vmcnt(2)" ::: "memory"); }
    __builtin_amdgcn_sched_barrier(0);
    __builtin_amdgcn_s_barrier();
    if (kt < 30) STAGE(kt + 2, (kt + 2) % 3);
    const int cur = kt % 3;

    #pragma unroll
    for (int ks = 0; ks < 2; ++ks) {
      f32x4 sf0[2] = {}, sf1[2] = {};
      __builtin_amdgcn_s_setprio(1);
      #pragma unroll
      for (int s = 0; s < 2; ++s) {
        bf16x8 kf0 = *(const bf16x8*)((const char*)Ks[cur] + (2 * ks * 16 + lr) * 128 +
                                      ((s * 64 + lg * 16) ^ ((lr & 7) << 4)));
        sf0[0] = __builtin_amdgcn_mfma_f32_16x16x32_bf16(kf0, qf[0][s], sf0[0], 0, 0, 0);
        sf0[1] = __builtin_amdgcn_mfma_f32_16x16x32_bf16(kf0, qf[1][s], sf0[1], 0, 0, 0);
        bf16x8 kf1 = *(const bf16x8*)((const char*)Ks[cur] + ((2 * ks + 1) * 16 + lr) * 128 +
                                      ((s * 64 + lg * 16) ^ ((lr & 7) << 4)));
        sf1[0] = __builtin_amdgcn_mfma_f32_16x16x32_bf16(kf1, qf[0][s], sf1[0], 0, 0, 0);
        sf1[1] = __builtin_amdgcn_mfma_f32_16x16x32_bf16(kf1, qf[1][s], sf1[1], 0, 0, 0);
      }
      __builtin_amdgcn_s_setprio(0);

      bf16x8 pa[2];
      #pragma unroll
      for (int m = 0; m < 2; ++m)
        #pragma unroll
        for (int j = 0; j < 4; ++j) {
          pa[m][j]     = (__bf16)__builtin_amdgcn_exp2f(sf0[m][j]);
          pa[m][4 + j] = (__bf16)__builtin_amdgcn_exp2f(sf1[m][j]);
        }

      __builtin_amdgcn_s_setprio(1);
      accl[0] = __builtin_amdgcn_mfma_f32_16x16x32_bf16(ones, pa[0], accl[0], 0, 0, 0);
      accl[1] = __builtin_amdgcn_mfma_f32_16x16x32_bf16(ones, pa[1], accl[1], 0, 0, 0);
      #pragma unroll
      for (int d = 0; d < 4; ++d) {
        const int rv = d * 16 + lr;
        bf16x8 vf = *(const bf16x8*)((const char*)Vs[cur] + rv * 128 +
                                     ((64 * ks + 16 * lg) ^ ((lr & 7) << 4)));
        acc[0][d] = __builtin_amdgcn_mfma_f32_16x16x32_bf16(vf, pa[0], acc[0][d], 0, 0, 0);
        acc[1][d] = __builtin_amdgcn_mfma_f32_16x16x32_bf16(vf, pa[1], acc[1][d], 0, 0, 0);
      }
      __builtin_amdgcn_s_setprio(0);
    }
  }

  #pragma unroll
  for (int m = 0; m < 2; ++m) {
    const float inv = 1.0f / accl[m][0];
    const int t = q0 + wave * 32 + m * 16 + lr;
    #pragma unroll
    for (int d = 0; d < 4; ++d) {
      bf16x4 ov;
      #pragma unroll
      for (int j = 0; j < 4; ++j) ov[j] = (__bf16)(acc[m][d][j] * inv);
      *(bf16x4*)&att[((size_t)b * 2048 + t) * 1024 + h * 64 + d * 16 + lg * 4] = ov;
    }
  }
#undef STAGE
}

extern "C" void kernel_launch(void* const* d_in, const int* in_sizes, int n_in,
                              void* d_out, int out_size, void* d_ws, size_t ws_size,
                              hipStream_t stream) {
  const float* x     = (const float*)d_in[0];
  const float* w_qkv = (const float*)d_in[1];
  const float* b_qkv = (const float*)d_in[2];
  const float* w_out = (const float*)d_in[3];
  const float* b_out = (const float*)d_in[4];
  float* out = (float*)d_out;

  char* ws = (char*)d_ws;
  const size_t MB = 1024 * 1024;
  u16* xb    = (u16*)(ws);             // 16 MB x bf16 -- dead after qkv gemm
  u16* attb  = xb;                     // alias: attn output reuses xb
  u16* wqkvt = (u16*)(ws + 16 * MB);   // 6 MB  [3072][1024]
  u16* woutt = (u16*)(ws + 22 * MB);   // 2 MB  [1024][1024]
  u16* qb    = (u16*)(ws + 24 * MB);   // 16 MB [bh][2048][64]
  u16* kb    = (u16*)(ws + 40 * MB);   // 16 MB
  u16* vtb   = (u16*)(ws + 56 * MB);   // 16 MB [bh][64][2048] (k-permuted V^T)

  // fused prep: cvt x (8192 blocks) + w_qkv transpose (3072) + w_out (1024)
  prep_kernel<<<12288, 256, 0, stream>>>(x, xb, w_qkv, wqkvt, w_out, woutt);

  // qkv GEMM (bf16 A); v written directly as k-permuted V^T
  gemm_kernel<0><<<dim3(8192 / 128, 3072 / 128), 256, 0, stream>>>(
      xb, wqkvt, b_qkv, qb, kb, vtb, nullptr, 3072, 1024);

  attn_kernel<<<dim3(64, 8), 512, 0, stream>>>(qb, kb, vtb, attb);

  gemm_kernel<1><<<dim3(8192 / 128, 1024 / 128), 256, 0, stream>>>(
      attb, woutt, b_out, nullptr, nullptr, nullptr, out, 1024, 1024);
}